// Round 1
// baseline (778.217 us; speedup 1.0000x reference)
//
#include <hip/hip_runtime.h>
#include <math.h>

// Problem constants (shapes fixed by setup_inputs)
#define BQ   8      // batch
#define CQ   128    // out channels
#define HQ   256
#define WQ   256
#define CR   64     // res2 channels
#define HR   512
#define WR   512
#define PK   768    // K*N oversampled points
#define NPTS 256    // final points per batch
#define BETA 192    // importance points
#define NCOV 64     // coverage points

// Bilinear combine, bit-exact association match with the numpy reference:
// ((v00*(1-wx))*(1-wy) + (v01*wx)*(1-wy)) + (v10*(1-wx))*wy + (v11*wx)*wy
__device__ __forceinline__ float bilin_ref(float v00, float v01, float v10, float v11,
                                           float wx, float wy) {
#pragma clang fp contract(off)
    float omwx = 1.0f - wx;
    float omwy = 1.0f - wy;
    return (v00 * omwx) * omwy + (v01 * wx) * omwy + (v10 * omwx) * wy + (v11 * wx) * wy;
}

// Bilinear sample of one channel plane with zero padding (align_corners=False).
__device__ __forceinline__ float sample_one(const float* __restrict__ plane, int H, int W,
                                            float px, float py) {
#pragma clang fp contract(off)
    float gx = px * (float)W - 0.5f;
    float gy = py * (float)H - 0.5f;
    float x0f = floorf(gx), y0f = floorf(gy);
    float wx = gx - x0f, wy = gy - y0f;
    int x0 = (int)x0f, y0 = (int)y0f;
    int x1 = x0 + 1, y1 = y0 + 1;
    bool xv0 = (x0 >= 0) & (x0 < W), xv1 = (x1 >= 0) & (x1 < W);
    bool yv0 = (y0 >= 0) & (y0 < H), yv1 = (y1 >= 0) & (y1 < H);
    float v00 = 0.f, v01 = 0.f, v10 = 0.f, v11 = 0.f;
    if (yv0 && xv0) v00 = plane[y0 * W + x0];
    if (yv0 && xv1) v01 = plane[y0 * W + x1];
    if (yv1 && xv0) v10 = plane[y1 * W + x0];
    if (yv1 && xv1) v11 = plane[y1 * W + x1];
    return bilin_ref(v00, v01, v10, v11, wx, wy);
}

// Kernel A: one wave (64 lanes) per oversampled point.
// Lane l loads channels l and l+64 at each valid corner; butterfly top-2 merge
// gives the per-corner top-2 over 128 channels (exact: selection only).
// Also writes the full interpolated 128-ch coarse feature per point (cache).
__global__ __launch_bounds__(256) void unc_coarse_kernel(
        const float* __restrict__ outm, const float* __restrict__ rand_over,
        float* __restrict__ unc, float* __restrict__ coarse_cache) {
#pragma clang fp contract(off)
    int gwave = (blockIdx.x * 256 + threadIdx.x) >> 6;   // point id in [0, BQ*PK)
    int lane = threadIdx.x & 63;
    if (gwave >= BQ * PK) return;
    int b = gwave / PK;

    float px = rand_over[gwave * 2 + 0];
    float py = rand_over[gwave * 2 + 1];
    float gx = px * 256.0f - 0.5f;
    float gy = py * 256.0f - 0.5f;
    float x0f = floorf(gx), y0f = floorf(gy);
    float wx = gx - x0f, wy = gy - y0f;
    int x0 = (int)x0f, y0 = (int)y0f;

    const float* base = outm + (size_t)b * CQ * HQ * WQ;
    float va[4], vb[4];     // raw values for ch=lane, ch=lane+64 (0 if corner invalid)
    float m1[4], m2[4];     // per-corner local top-2 (-inf if invalid)
    bool vld[4];
#pragma unroll
    for (int k = 0; k < 4; ++k) {
        int yy = y0 + (k >> 1);
        int xx = x0 + (k & 1);
        bool valid = (xx >= 0) && (xx < WQ) && (yy >= 0) && (yy < HQ);
        vld[k] = valid;
        float a = 0.0f, c = 0.0f;
        if (valid) {
            size_t off = (size_t)yy * WQ + xx;
            a = base[(size_t)lane * (HQ * WQ) + off];
            c = base[(size_t)(lane + 64) * (HQ * WQ) + off];
        }
        va[k] = a;
        vb[k] = c;
        m1[k] = valid ? fmaxf(a, c) : -INFINITY;
        m2[k] = valid ? fminf(a, c) : -INFINITY;
    }
    // wave-wide top-2 per corner (exact; no arithmetic rounding)
#pragma unroll
    for (int off = 1; off < 64; off <<= 1) {
#pragma unroll
        for (int k = 0; k < 4; ++k) {
            float o1 = __shfl_xor(m1[k], off, 64);
            float o2 = __shfl_xor(m2[k], off, 64);
            float hi = fmaxf(m1[k], o1);
            float lo = fminf(m1[k], o1);
            m2[k] = fmaxf(lo, fmaxf(m2[k], o2));
            m1[k] = hi;
        }
    }
    // cache interpolated coarse features for this lane's two channels
    float c0 = bilin_ref(va[0], va[1], va[2], va[3], wx, wy);
    float c1 = bilin_ref(vb[0], vb[1], vb[2], vb[3], wx, wy);
    float* cc = coarse_cache + (size_t)gwave * CQ;
    cc[lane] = c0;
    cc[lane + 64] = c1;

    if (lane == 0) {
        float t0[4], t1[4];
#pragma unroll
        for (int k = 0; k < 4; ++k) {
            t0[k] = vld[k] ? m1[k] : 0.0f;   // matches reference's v*valid
            t1[k] = vld[k] ? m2[k] : 0.0f;
        }
        float V0 = bilin_ref(t0[0], t0[1], t0[2], t0[3], wx, wy);
        float V1 = bilin_ref(t1[0], t1[1], t1[2], t1[3], wx, wy);
        unc[gwave] = -(V0 - V1);
    }
}

// Kernel B: per-batch full bitonic sort of 768 (padded to 1024) uncertainty keys.
// Order: descending value, ties -> lower index first (== lax.top_k semantics).
__global__ __launch_bounds__(256) void topk_kernel(
        const float* __restrict__ unc, const float* __restrict__ rand_over,
        const float* __restrict__ rand_cov, float* __restrict__ points,
        int* __restrict__ selIdx) {
    __shared__ float sv[1024];
    __shared__ int si[1024];
    int b = blockIdx.x;
    int tid = threadIdx.x;
    for (int i = tid; i < 1024; i += 256) {
        if (i < PK) { sv[i] = unc[b * PK + i]; si[i] = i; }
        else        { sv[i] = -INFINITY;       si[i] = 0x7FFFFFFF; }
    }
    __syncthreads();
    for (int k = 2; k <= 1024; k <<= 1) {
        for (int j = k >> 1; j >= 1; j >>= 1) {
            for (int t = tid; t < 512; t += 256) {
                int i = ((t & ~(j - 1)) << 1) | (t & (j - 1));
                int ixj = i | j;
                float vA = sv[i], vB = sv[ixj];
                int iA = si[i], iB = si[ixj];
                bool aFirst = (vA > vB) || (vA == vB && iA < iB);
                bool up = ((i & k) == 0);
                if (up != aFirst) {
                    sv[i] = vB; sv[ixj] = vA;
                    si[i] = iB; si[ixj] = iA;
                }
            }
            __syncthreads();
        }
    }
    if (tid < NPTS) {
        float px, py; int s;
        if (tid < BETA) {
            s = si[tid];
            px = rand_over[(b * PK + s) * 2 + 0];
            py = rand_over[(b * PK + s) * 2 + 1];
        } else {
            s = -1;
            px = rand_cov[(b * NCOV + (tid - BETA)) * 2 + 0];
            py = rand_cov[(b * NCOV + (tid - BETA)) * 2 + 1];
        }
        points[(b * NPTS + tid) * 2 + 0] = px;
        points[(b * NPTS + tid) * 2 + 1] = py;
        selIdx[b * NPTS + tid] = s;
    }
}

// Kernel C: one block (192 threads) per final point.
// t<128: coarse channel t (from cache if importance point, else gather from out);
// t>=128: fine channel t-128 gathered from res2. Then 128x192 dot per out channel.
__global__ __launch_bounds__(192) void rend_kernel(
        const float* __restrict__ outm, const float* __restrict__ res2,
        const float* __restrict__ weight, const float* __restrict__ bias,
        const float* __restrict__ points, const int* __restrict__ selIdx,
        const float* __restrict__ coarse_cache, float* __restrict__ rend) {
    __shared__ float feat[192];
    int blk = blockIdx.x;
    int b = blk >> 8;
    int p = blk & 255;
    int t = threadIdx.x;
    float px = points[(b * NPTS + p) * 2 + 0];
    float py = points[(b * NPTS + p) * 2 + 1];
    int src = selIdx[b * NPTS + p];
    if (t < 128) {
        float v;
        if (src >= 0) {
            v = coarse_cache[((size_t)b * PK + src) * CQ + t];
        } else {
            v = sample_one(outm + ((size_t)b * CQ + t) * (HQ * WQ), HQ, WQ, px, py);
        }
        feat[t] = v;
    } else {
        int c = t - 128;
        feat[t] = sample_one(res2 + ((size_t)b * CR + c) * (HR * WR), HR, WR, px, py);
    }
    __syncthreads();
    if (t < 128) {
        const float* wrow = weight + t * 192;
        float acc = 0.0f;
#pragma unroll 4
        for (int c = 0; c < 192; ++c) acc = fmaf(wrow[c], feat[c], acc);
        rend[((size_t)b * 128 + t) * NPTS + p] = acc + bias[t];
    }
}

extern "C" void kernel_launch(void* const* d_in, const int* in_sizes, int n_in,
                              void* d_out, int out_size, void* d_ws, size_t ws_size,
                              hipStream_t stream) {
    // inputs: 0=x (unused; N=4096/16=256 fixed), 1=res2, 2=out, 3=rand_over,
    //         4=rand_cov, 5=weight, 6=bias
    const float* res2      = (const float*)d_in[1];
    const float* outm      = (const float*)d_in[2];
    const float* rand_over = (const float*)d_in[3];
    const float* rand_cov  = (const float*)d_in[4];
    const float* weight    = (const float*)d_in[5];
    const float* bias      = (const float*)d_in[6];

    float* rend   = (float*)d_out;                       // [8,128,256]
    float* points = rend + (size_t)BQ * 128 * NPTS;      // [8,256,2]

    float* unc          = (float*)d_ws;                          // [8*768]
    float* coarse_cache = unc + BQ * PK;                         // [8*768,128]
    int*   selIdx       = (int*)(coarse_cache + (size_t)BQ * PK * CQ);  // [8*256]

    unc_coarse_kernel<<<(BQ * PK) / 4, 256, 0, stream>>>(outm, rand_over, unc, coarse_cache);
    topk_kernel<<<BQ, 256, 0, stream>>>(unc, rand_over, rand_cov, points, selIdx);
    rend_kernel<<<BQ * NPTS, 192, 0, stream>>>(outm, res2, weight, bias, points, selIdx,
                                               coarse_cache, rend);
}

// Round 2
// 758.325 us; speedup vs baseline: 1.0262x; 1.0262x over previous
//
#include <hip/hip_runtime.h>
#include <math.h>

// Problem constants (shapes fixed by setup_inputs)
#define BQ   8      // batch
#define CQ   128    // out channels
#define HQ   256
#define WQ   256
#define CR   64     // res2 channels
#define HR   512
#define WR   512
#define PK   768    // K*N oversampled points
#define NPTS 256    // final points per batch
#define BETA 192    // importance points
#define NCOV 64     // coverage points

// Bilinear combine, bit-exact association match with the numpy reference:
// ((v00*(1-wx))*(1-wy) + (v01*wx)*(1-wy)) + (v10*(1-wx))*wy + (v11*wx)*wy
__device__ __forceinline__ float bilin_ref(float v00, float v01, float v10, float v11,
                                           float wx, float wy) {
#pragma clang fp contract(off)
    float omwx = 1.0f - wx;
    float omwy = 1.0f - wy;
    return (v00 * omwx) * omwy + (v01 * wx) * omwy + (v10 * omwx) * wy + (v11 * wx) * wy;
}

// Branchless bilinear sample with zero padding (align_corners=False).
// Matches reference exactly: gather at clipped index, multiply by valid mask.
__device__ __forceinline__ float sample_one(const float* __restrict__ plane, int H, int W,
                                            float px, float py) {
#pragma clang fp contract(off)
    float gx = px * (float)W - 0.5f;
    float gy = py * (float)H - 0.5f;
    float x0f = floorf(gx), y0f = floorf(gy);
    float wx = gx - x0f, wy = gy - y0f;
    int x0 = (int)x0f, y0 = (int)y0f;
    int x1 = x0 + 1, y1 = y0 + 1;
    float xv0 = (x0 >= 0 && x0 < W) ? 1.0f : 0.0f;
    float xv1 = (x1 >= 0 && x1 < W) ? 1.0f : 0.0f;
    float yv0 = (y0 >= 0 && y0 < H) ? 1.0f : 0.0f;
    float yv1 = (y1 >= 0 && y1 < H) ? 1.0f : 0.0f;
    int xi0 = min(max(x0, 0), W - 1), xi1 = min(max(x1, 0), W - 1);
    int yi0 = min(max(y0, 0), H - 1), yi1 = min(max(y1, 0), H - 1);
    // all four loads issue unconditionally (MLP), masked after
    float v00 = plane[yi0 * W + xi0] * (yv0 * xv0);
    float v01 = plane[yi0 * W + xi1] * (yv0 * xv1);
    float v10 = plane[yi1 * W + xi0] * (yv1 * xv0);
    float v11 = plane[yi1 * W + xi1] * (yv1 * xv1);
    return bilin_ref(v00, v01, v10, v11, wx, wy);
}

// Kernel A: one wave (64 lanes) per oversampled point.
// Lane l loads channels l and l+64 at each corner (clamped addresses, no
// branches -> 8 loads in flight); butterfly top-2 merge over 128 channels
// (exact: selection only, invalid corners zeroed at the interpolation step).
// Also writes the full interpolated 128-ch coarse feature per point (cache).
__global__ __launch_bounds__(256) void unc_coarse_kernel(
        const float* __restrict__ outm, const float* __restrict__ rand_over,
        float* __restrict__ unc, float* __restrict__ coarse_cache) {
#pragma clang fp contract(off)
    int gwave = (blockIdx.x * 256 + threadIdx.x) >> 6;   // point id in [0, BQ*PK)
    int lane = threadIdx.x & 63;
    if (gwave >= BQ * PK) return;
    int b = gwave / PK;

    float px = rand_over[gwave * 2 + 0];
    float py = rand_over[gwave * 2 + 1];
    float gx = px * 256.0f - 0.5f;
    float gy = py * 256.0f - 0.5f;
    float x0f = floorf(gx), y0f = floorf(gy);
    float wx = gx - x0f, wy = gy - y0f;
    int x0 = (int)x0f, y0 = (int)y0f;
    int x1 = x0 + 1, y1 = y0 + 1;

    float vf[4];
    vf[0] = ((y0 >= 0 && y0 < HQ) && (x0 >= 0 && x0 < WQ)) ? 1.0f : 0.0f;
    vf[1] = ((y0 >= 0 && y0 < HQ) && (x1 >= 0 && x1 < WQ)) ? 1.0f : 0.0f;
    vf[2] = ((y1 >= 0 && y1 < HQ) && (x0 >= 0 && x0 < WQ)) ? 1.0f : 0.0f;
    vf[3] = ((y1 >= 0 && y1 < HQ) && (x1 >= 0 && x1 < WQ)) ? 1.0f : 0.0f;
    int xi0 = min(max(x0, 0), WQ - 1), xi1 = min(max(x1, 0), WQ - 1);
    int yi0 = min(max(y0, 0), HQ - 1), yi1 = min(max(y1, 0), HQ - 1);
    int off[4];
    off[0] = yi0 * WQ + xi0; off[1] = yi0 * WQ + xi1;
    off[2] = yi1 * WQ + xi0; off[3] = yi1 * WQ + xi1;

    const float* p0 = outm + (size_t)b * CQ * HQ * WQ + (size_t)lane * (HQ * WQ);
    const float* p1 = p0 + (size_t)64 * (HQ * WQ);
    float a[4], c[4];
#pragma unroll
    for (int k = 0; k < 4; ++k) { a[k] = p0[off[k]]; c[k] = p1[off[k]]; }

    float m1[4], m2[4];   // per-corner top-2 over this lane's 2 channels (raw values)
#pragma unroll
    for (int k = 0; k < 4; ++k) { m1[k] = fmaxf(a[k], c[k]); m2[k] = fminf(a[k], c[k]); }
    // wave-wide top-2 per corner (exact; no arithmetic rounding)
#pragma unroll
    for (int sft = 1; sft < 64; sft <<= 1) {
#pragma unroll
        for (int k = 0; k < 4; ++k) {
            float o1 = __shfl_xor(m1[k], sft, 64);
            float o2 = __shfl_xor(m2[k], sft, 64);
            float hi = fmaxf(m1[k], o1);
            float lo = fminf(m1[k], o1);
            m2[k] = fmaxf(lo, fmaxf(m2[k], o2));
            m1[k] = hi;
        }
    }
    // cache interpolated coarse features (masked corners, ref association)
    float c0 = bilin_ref(a[0] * vf[0], a[1] * vf[1], a[2] * vf[2], a[3] * vf[3], wx, wy);
    float c1 = bilin_ref(c[0] * vf[0], c[1] * vf[1], c[2] * vf[2], c[3] * vf[3], wx, wy);
    float* cc = coarse_cache + (size_t)gwave * CQ;
    cc[lane] = c0;
    cc[lane + 64] = c1;

    if (lane == 0) {
        // invalid corners contribute 0 (reference: v*valid); garbage from the
        // clamped load is discarded here, selection above was value-exact.
        float V0 = bilin_ref(vf[0] != 0.f ? m1[0] : 0.f, vf[1] != 0.f ? m1[1] : 0.f,
                             vf[2] != 0.f ? m1[2] : 0.f, vf[3] != 0.f ? m1[3] : 0.f, wx, wy);
        float V1 = bilin_ref(vf[0] != 0.f ? m2[0] : 0.f, vf[1] != 0.f ? m2[1] : 0.f,
                             vf[2] != 0.f ? m2[2] : 0.f, vf[3] != 0.f ? m2[3] : 0.f, wx, wy);
        unc[gwave] = -(V0 - V1);
    }
}

// Kernel B: per-batch full bitonic sort of 768 (padded to 1024) uncertainty keys.
// Order: descending value, ties -> lower index first (== lax.top_k semantics).
__global__ __launch_bounds__(256) void topk_kernel(
        const float* __restrict__ unc, const float* __restrict__ rand_over,
        const float* __restrict__ rand_cov, float* __restrict__ points,
        int* __restrict__ selIdx) {
    __shared__ float sv[1024];
    __shared__ int si[1024];
    int b = blockIdx.x;
    int tid = threadIdx.x;
    for (int i = tid; i < 1024; i += 256) {
        if (i < PK) { sv[i] = unc[b * PK + i]; si[i] = i; }
        else        { sv[i] = -INFINITY;       si[i] = 0x7FFFFFFF; }
    }
    __syncthreads();
    for (int k = 2; k <= 1024; k <<= 1) {
        for (int j = k >> 1; j >= 1; j >>= 1) {
            for (int t = tid; t < 512; t += 256) {
                int i = ((t & ~(j - 1)) << 1) | (t & (j - 1));
                int ixj = i | j;
                float vA = sv[i], vB = sv[ixj];
                int iA = si[i], iB = si[ixj];
                bool aFirst = (vA > vB) || (vA == vB && iA < iB);
                bool up = ((i & k) == 0);
                if (up != aFirst) {
                    sv[i] = vB; sv[ixj] = vA;
                    si[i] = iB; si[ixj] = iA;
                }
            }
            __syncthreads();
        }
    }
    if (tid < NPTS) {
        float px, py; int s;
        if (tid < BETA) {
            s = si[tid];
            px = rand_over[(b * PK + s) * 2 + 0];
            py = rand_over[(b * PK + s) * 2 + 1];
        } else {
            s = -1;
            px = rand_cov[(b * NCOV + (tid - BETA)) * 2 + 0];
            py = rand_cov[(b * NCOV + (tid - BETA)) * 2 + 1];
        }
        points[(b * NPTS + tid) * 2 + 0] = px;
        points[(b * NPTS + tid) * 2 + 1] = py;
        selIdx[b * NPTS + tid] = s;
    }
}

// Tiny transpose: wT[c][o] = weight[o][c]  (192x128 floats, 98 KB)
__global__ __launch_bounds__(256) void transpose_w_kernel(
        const float* __restrict__ w, float* __restrict__ wT) {
    int i = blockIdx.x * 256 + threadIdx.x;
    if (i < 128 * 192) {
        int o = i / 192, c = i % 192;
        wT[c * 128 + o] = w[i];   // coalesced read, scattered write (one-time, tiny)
    }
}

// Kernel C: one block (192 threads) per final point.
// t<128: coarse channel t (from cache if importance point, else gather from out);
// t>=128: fine channel t-128 gathered from res2. Then per-out-channel dot with
// COALESCED transposed-weight columns (wT[c][o]: lanes read consecutive floats).
__global__ __launch_bounds__(192) void rend_kernel(
        const float* __restrict__ outm, const float* __restrict__ res2,
        const float* __restrict__ wT, const float* __restrict__ bias,
        const float* __restrict__ points, const int* __restrict__ selIdx,
        const float* __restrict__ coarse_cache, float* __restrict__ rend) {
    __shared__ float feat[192];
    int blk = blockIdx.x;
    int b = blk >> 8;
    int p = blk & 255;
    int t = threadIdx.x;
    float px = points[(b * NPTS + p) * 2 + 0];
    float py = points[(b * NPTS + p) * 2 + 1];
    int src = selIdx[b * NPTS + p];
    if (t < 128) {
        float v;
        if (src >= 0) {
            v = coarse_cache[((size_t)b * PK + src) * CQ + t];
        } else {
            v = sample_one(outm + ((size_t)b * CQ + t) * (HQ * WQ), HQ, WQ, px, py);
        }
        feat[t] = v;
    } else {
        int c = t - 128;
        feat[t] = sample_one(res2 + ((size_t)b * CR + c) * (HR * WR), HR, WR, px, py);
    }
    __syncthreads();
    if (t < 128) {
        float acc = 0.0f;
#pragma unroll 8
        for (int c = 0; c < 192; ++c) acc = fmaf(wT[c * 128 + t], feat[c], acc);
        rend[((size_t)b * 128 + t) * NPTS + p] = acc + bias[t];
    }
}

extern "C" void kernel_launch(void* const* d_in, const int* in_sizes, int n_in,
                              void* d_out, int out_size, void* d_ws, size_t ws_size,
                              hipStream_t stream) {
    // inputs: 0=x (unused; N=4096/16=256 fixed), 1=res2, 2=out, 3=rand_over,
    //         4=rand_cov, 5=weight, 6=bias
    const float* res2      = (const float*)d_in[1];
    const float* outm      = (const float*)d_in[2];
    const float* rand_over = (const float*)d_in[3];
    const float* rand_cov  = (const float*)d_in[4];
    const float* weight    = (const float*)d_in[5];
    const float* bias      = (const float*)d_in[6];

    float* rend   = (float*)d_out;                       // [8,128,256]
    float* points = rend + (size_t)BQ * 128 * NPTS;      // [8,256,2]

    float* unc          = (float*)d_ws;                          // [8*768]
    float* coarse_cache = unc + BQ * PK;                         // [8*768,128]
    int*   selIdx       = (int*)(coarse_cache + (size_t)BQ * PK * CQ);  // [8*256]
    float* wT           = (float*)(selIdx + BQ * NPTS);          // [192,128]

    transpose_w_kernel<<<(128 * 192 + 255) / 256, 256, 0, stream>>>(weight, wT);
    unc_coarse_kernel<<<(BQ * PK) / 4, 256, 0, stream>>>(outm, rand_over, unc, coarse_cache);
    topk_kernel<<<BQ, 256, 0, stream>>>(unc, rand_over, rand_cov, points, selIdx);
    rend_kernel<<<BQ * NPTS, 192, 0, stream>>>(outm, res2, wT, bias, points, selIdx,
                                               coarse_cache, rend);
}